// Round 7
// baseline (105.118 us; speedup 1.0000x reference)
//
#include <hip/hip_runtime.h>

#define BATCH 4096
#define SEQ   80
#define EMBED 100
#define UNITS 64
#define NTILE (BATCH / 16)     // 256 batch tiles of 16 rows
#define NBLK  (NTILE / 2)      // 128 blocks, 2 tiles (A,B) per block

typedef float f32x4  __attribute__((ext_vector_type(4)));
typedef short bf16x8 __attribute__((ext_vector_type(8)));

#define MFMA16 __builtin_amdgcn_mfma_f32_16x16x32_bf16

// ---- ws layout (bytes) ----
#define EMB_OFF 0u           // ushort[10000*128] = 2,560,000 B (zero-padded K)
#define W1T_OFF 2560000u     // ushort[64*128]
#define U1T_OFF 2576384u     // ushort[64*64]
#define W2T_OFF 2584576u
#define U2T_OFF 2592768u     // end ~2.6 MB (L2-resident)

__device__ __forceinline__ unsigned f2bfu(float f) {
    union { float f; unsigned u; } x; x.f = f;
    return (x.u + 0x7fffu + ((x.u >> 16) & 1u)) >> 16;   // RNE (prep only)
}
__device__ __forceinline__ unsigned cvtpk(float lo, float hi) {
    unsigned r;
    asm("v_cvt_pk_bf16_f32 %0, %1, %2" : "=v"(r) : "v"(lo), "v"(hi));
    return r;
}
// branch-free exact-tails tanh: 1 - 2/(e^{2x}+1)
__device__ __forceinline__ float fast_tanh(float x) {
    float e = __builtin_amdgcn_exp2f(x * 2.8853900817779268f);   // e^{2x}
    float r = __builtin_amdgcn_rcpf(e + 1.0f);
    return __builtin_fmaf(-2.0f, r, 1.0f);
}

// ---------------------------------------------------------------------------
// prep: bf16 tables — emb padded to K=128, transposed W1/U1/W2/U2.
// ---------------------------------------------------------------------------
__global__ __launch_bounds__(256) void prep_kernel(
    const float* __restrict__ emb, const float* __restrict__ W1,
    const float* __restrict__ U1,  const float* __restrict__ W2,
    const float* __restrict__ U2,  char* __restrict__ ws)
{
    ushort* emb_bf = (ushort*)(ws + EMB_OFF);
    ushort* w1t    = (ushort*)(ws + W1T_OFF);
    ushort* u1t    = (ushort*)(ws + U1T_OFF);
    ushort* w2t    = (ushort*)(ws + W2T_OFF);
    ushort* u2t    = (ushort*)(ws + U2T_OFF);
    const int tid    = blockIdx.x * 256 + threadIdx.x;
    const int stride = gridDim.x * 256;

    for (int i = tid; i < 10000 * 16; i += stride) {
        const int r = i >> 4, kc = (i & 15) * 8;
        unsigned w[4];
        #pragma unroll
        for (int p = 0; p < 4; ++p) {
            const int k0 = kc + 2 * p;
            unsigned lo = (k0     < EMBED) ? f2bfu(emb[r * EMBED + k0])     : 0u;
            unsigned hi = (k0 + 1 < EMBED) ? f2bfu(emb[r * EMBED + k0 + 1]) : 0u;
            w[p] = lo | (hi << 16);
        }
        uint4 v; v.x = w[0]; v.y = w[1]; v.z = w[2]; v.w = w[3];
        *(uint4*)(emb_bf + (size_t)r * 128 + kc) = v;
    }
    for (int i = tid; i < UNITS * 128; i += stride) {
        const int u = i >> 7, k = i & 127;
        w1t[i] = (k < EMBED) ? (ushort)f2bfu(W1[k * UNITS + u]) : (ushort)0;
    }
    for (int i = tid; i < UNITS * UNITS; i += stride) {
        const int u = i >> 6, k = i & 63;
        u1t[i] = (ushort)f2bfu(U1[k * UNITS + u]);
        w2t[i] = (ushort)f2bfu(W2[k * UNITS + u]);
        u2t[i] = (ushort)f2bfu(U2[k * UNITS + u]);
    }
}

// ---------------------------------------------------------------------------
// rnn: fused proj + scan. 8 waves/block = 2 independent batch tiles x 4-way
// M-split -> 2 co-resident waves per SIMD whose stalls interleave.
// One barrier per timestep publishes BOTH tiles' {h1[t+1], h2[t]}.
// Per-tile math identical to R5 (verified): parallel-layer phase.
// ---------------------------------------------------------------------------
__global__ __launch_bounds__(512, 2) void rnn_kernel(
    const int*    __restrict__ tokens,
    const ushort* __restrict__ emb_bf,
    const ushort* __restrict__ w1t,
    const ushort* __restrict__ u1t,
    const ushort* __restrict__ w2t,
    const ushort* __restrict__ u2t,
    const float*  __restrict__ b1,
    const float*  __restrict__ b2,
    const float*  __restrict__ Wo,
    const float*  __restrict__ bo,
    float*        __restrict__ out)
{
    __shared__ __align__(16) char h1L[2][2][2048];   // [tile][buf][16b x 64u bf16]
    __shared__ __align__(16) char h2L[2][2][2048];
    __shared__ float headp[2][4][16];

    const int lane = threadIdx.x & 63;
    const int W    = threadIdx.x >> 6;    // 0..7
    const int tile = W >> 2;              // 0 = A, 1 = B
    const int w    = W & 3;               // unit-slice id
    const int m15  = lane & 15;
    const int kgrp = lane >> 4;
    const int swz  = (m15 & 7) << 4;
    const int wg   = blockIdx.x * 2 + tile;
    const long b80 = (long)(wg * 16 + m15) * SEQ;

    char* const h1P0 = h1L[tile][0]; char* const h1P1 = h1L[tile][1];
    char* const h2P0 = h2L[tile][0]; char* const h2P1 = h2L[tile][1];

    // zero h2[-1] (buf 0) for both tiles
    {
        uint4 z = {0u, 0u, 0u, 0u};
        const int tid = threadIdx.x;
        if (tid < 128)            ((uint4*)h2L[0][0])[tid]       = z;
        else if (tid < 256)       ((uint4*)h2L[1][0])[tid - 128] = z;
    }

    // weight A-fragments for this wave's unit slice (shared across tiles)
    const int urow = 16 * w + m15;
    bf16x8 aW1[4], aU1[2], aW2[2], aU2[2];
    #pragma unroll
    for (int ks = 0; ks < 4; ++ks)
        aW1[ks] = *(const bf16x8*)(w1t + urow * 128 + kgrp * 8 + 32 * ks);
    #pragma unroll
    for (int ks = 0; ks < 2; ++ks) {
        aU1[ks] = *(const bf16x8*)(u1t + urow * 64 + kgrp * 8 + 32 * ks);
        aW2[ks] = *(const bf16x8*)(w2t + urow * 64 + kgrp * 8 + 32 * ks);
        aU2[ks] = *(const bf16x8*)(u2t + urow * 64 + kgrp * 8 + 32 * ks);
    }
    const int ubase = 16 * w + 4 * kgrp;
    const f32x4 b1c = *(const f32x4*)(b1 + ubase);
    const f32x4 b2c = *(const f32x4*)(b2 + ubase);

    // ---- emb double-buffer prologue (per tile) ----
    bf16x8 eX0, eX1, eX2, eX3, eY0, eY1, eY2, eY3;
    {
        const int tk0 = tokens[b80 + 0];
        const ushort* er = emb_bf + (size_t)tk0 * 128 + kgrp * 8;
        eX0 = *(const bf16x8*)(er);      eX1 = *(const bf16x8*)(er + 32);
        eX2 = *(const bf16x8*)(er + 64); eX3 = *(const bf16x8*)(er + 96);
    }
    {
        const int tk1 = tokens[b80 + 1];
        const ushort* er = emb_bf + (size_t)tk1 * 128 + kgrp * 8;
        eY0 = *(const bf16x8*)(er);      eY1 = *(const bf16x8*)(er + 32);
        eY2 = *(const bf16x8*)(er + 64); eY3 = *(const bf16x8*)(er + 96);
    }
    int tokX = tokens[b80 + 2];
    int tokY = tokens[b80 + 3];

    // ---- prologue: h1[0] = tanh(b1 + W1 emb[0]) -> buf 0 ----
    {
        f32x4 dH = b1c;
        dH = MFMA16(aW1[0], eX0, dH, 0, 0, 0);
        dH = MFMA16(aW1[1], eX1, dH, 0, 0, 0);
        dH = MFMA16(aW1[2], eX2, dH, 0, 0, 0);
        dH = MFMA16(aW1[3], eX3, dH, 0, 0, 0);
        const ushort* er = emb_bf + (size_t)tokX * 128 + kgrp * 8;
        eX0 = *(const bf16x8*)(er);      eX1 = *(const bf16x8*)(er + 32);
        eX2 = *(const bf16x8*)(er + 64); eX3 = *(const bf16x8*)(er + 96);
        tokX = tokens[b80 + 4];
        float t0 = fast_tanh(dH[0]), t1 = fast_tanh(dH[1]);
        float t2 = fast_tanh(dH[2]), t3 = fast_tanh(dH[3]);
        uint2 pk; pk.x = cvtpk(t0, t1); pk.y = cvtpk(t2, t3);
        *(uint2*)(h1P0 + m15 * 128 + ((32 * w + 8 * kgrp) ^ swz)) = pk;
    }
    asm volatile("s_waitcnt lgkmcnt(0)" ::: "memory");
    __builtin_amdgcn_s_barrier();

    float d2f0 = 0.f, d2f1 = 0.f, d2f2 = 0.f, d2f3 = 0.f;

#define LBAR() do { asm volatile("s_waitcnt lgkmcnt(0)" ::: "memory"); \
                    __builtin_amdgcn_s_barrier(); } while (0)
// Phase T (this tile): reads {h1[T], h2[T-1]} from bufs P, computes
//   h2[T] = tanh(b2 + W2 h1[T] + U2 h2[T-1]);  h1[T+1] = tanh(b1 + W1 emb[T+1] + U1 h1[T])
// writes both to bufs Q; block-wide barrier covers both tiles.
#define PHASE(T, E0, E1, E2, E3, TOK, H1P, H2P, H1Q, H2Q)                        \
  {                                                                              \
    bf16x8 bh1a = *(const bf16x8*)(H1P + m15 * 128 + ((kgrp * 16     ) ^ swz));  \
    bf16x8 bh1b = *(const bf16x8*)(H1P + m15 * 128 + ((kgrp * 16 + 64) ^ swz));  \
    bf16x8 bh2a = *(const bf16x8*)(H2P + m15 * 128 + ((kgrp * 16     ) ^ swz));  \
    bf16x8 bh2b = *(const bf16x8*)(H2P + m15 * 128 + ((kgrp * 16 + 64) ^ swz));  \
    f32x4 dH = b1c;                                                              \
    dH = MFMA16(aW1[0], E0, dH, 0, 0, 0);                                        \
    dH = MFMA16(aW1[1], E1, dH, 0, 0, 0);                                        \
    dH = MFMA16(aW1[2], E2, dH, 0, 0, 0);                                        \
    dH = MFMA16(aW1[3], E3, dH, 0, 0, 0);                                        \
    {   /* refill this slot with emb[T+3] */                                     \
        const ushort* er = emb_bf + (size_t)TOK * 128 + kgrp * 8;                \
        E0 = *(const bf16x8*)(er);      E1 = *(const bf16x8*)(er + 32);          \
        E2 = *(const bf16x8*)(er + 64); E3 = *(const bf16x8*)(er + 96);          \
    }                                                                            \
    TOK = tokens[b80 + ((T) + 5 < SEQ ? (T) + 5 : SEQ - 1)];                     \
    f32x4 dC = b2c;                                                              \
    dC = MFMA16(aW2[0], bh1a, dC, 0, 0, 0);                                      \
    dC = MFMA16(aW2[1], bh1b, dC, 0, 0, 0);                                      \
    f32x4 dD = {0.f, 0.f, 0.f, 0.f};                                             \
    dD = MFMA16(aU2[0], bh2a, dD, 0, 0, 0);                                      \
    dD = MFMA16(aU2[1], bh2b, dD, 0, 0, 0);                                      \
    f32x4 dB = {0.f, 0.f, 0.f, 0.f};                                             \
    dB = MFMA16(aU1[0], bh1a, dB, 0, 0, 0);                                      \
    dB = MFMA16(aU1[1], bh1b, dB, 0, 0, 0);                                      \
    float n0 = fast_tanh(dH[0] + dB[0]);                                         \
    float n1 = fast_tanh(dH[1] + dB[1]);                                         \
    float n2 = fast_tanh(dH[2] + dB[2]);                                         \
    float n3 = fast_tanh(dH[3] + dB[3]);                                         \
    d2f0 = fast_tanh(dC[0] + dD[0]);                                             \
    d2f1 = fast_tanh(dC[1] + dD[1]);                                             \
    d2f2 = fast_tanh(dC[2] + dD[2]);                                             \
    d2f3 = fast_tanh(dC[3] + dD[3]);                                             \
    {                                                                            \
        uint2 pk; pk.x = cvtpk(n0, n1); pk.y = cvtpk(n2, n3);                    \
        *(uint2*)(H1Q + m15 * 128 + ((32 * w + 8 * kgrp) ^ swz)) = pk;           \
    }                                                                            \
    {                                                                            \
        uint2 pk; pk.x = cvtpk(d2f0, d2f1); pk.y = cvtpk(d2f2, d2f3);            \
        *(uint2*)(H2Q + m15 * 128 + ((32 * w + 8 * kgrp) ^ swz)) = pk;           \
    }                                                                            \
    LBAR();                                                                      \
  }

    for (int t = 0; t < SEQ; t += 2) {
        PHASE(t,     eY0, eY1, eY2, eY3, tokY, h1P0, h2P0, h1P1, h2P1)
        PHASE(t + 1, eX0, eX1, eX2, eX3, tokX, h1P1, h2P1, h1P0, h2P0)
    }
#undef PHASE
#undef LBAR

    // ---- head: out[b] = sigmoid(h2[79] @ Wo + bo) ----
    const f32x4 woc = *(const f32x4*)(Wo + ubase);
    float p = d2f0 * woc[0] + d2f1 * woc[1] + d2f2 * woc[2] + d2f3 * woc[3];
    p += __shfl_xor(p, 16, 64);
    p += __shfl_xor(p, 32, 64);
    if (lane < 16) headp[tile][w][lane] = p;
    __syncthreads();
    if (threadIdx.x < 32) {
        const int ti = threadIdx.x >> 4, bi = threadIdx.x & 15;
        const float z = headp[ti][0][bi] + headp[ti][1][bi]
                      + headp[ti][2][bi] + headp[ti][3][bi] + bo[0];
        const float e = __builtin_amdgcn_exp2f(-z * 1.4426950408889634f);
        out[(blockIdx.x * 2 + ti) * 16 + bi] = __builtin_amdgcn_rcpf(1.0f + e);
    }
}

extern "C" void kernel_launch(void* const* d_in, const int* in_sizes, int n_in,
                              void* d_out, int out_size, void* d_ws, size_t ws_size,
                              hipStream_t stream) {
    const int*   tokens = (const int*)  d_in[0];
    const float* emb    = (const float*)d_in[1];
    const float* W1     = (const float*)d_in[2];
    const float* U1     = (const float*)d_in[3];
    const float* b1     = (const float*)d_in[4];
    const float* W2     = (const float*)d_in[5];
    const float* U2     = (const float*)d_in[6];
    const float* b2     = (const float*)d_in[7];
    const float* Wo     = (const float*)d_in[8];
    const float* bo     = (const float*)d_in[9];
    float* out = (float*)d_out;
    char*  ws  = (char*)d_ws;

    prep_kernel<<<640, 256, 0, stream>>>(emb, W1, U1, W2, U2, ws);
    rnn_kernel<<<NBLK, 512, 0, stream>>>(
        tokens,
        (const ushort*)(ws + EMB_OFF), (const ushort*)(ws + W1T_OFF),
        (const ushort*)(ws + U1T_OFF), (const ushort*)(ws + W2T_OFF),
        (const ushort*)(ws + U2T_OFF),
        b1, b2, Wo, bo, out);
}

// Round 8
// 89.630 us; speedup vs baseline: 1.1728x; 1.1728x over previous
//
#include <hip/hip_runtime.h>

#define BATCH 4096
#define SEQ   80
#define EMBED 100
#define UNITS 64
#define NTILE (BATCH / 16)      // 256 batch tiles of 16 rows
#define NTASK (SEQ * NTILE)     // 20480 (t, tile) proj tasks

typedef float f32x4  __attribute__((ext_vector_type(4)));
typedef short bf16x8 __attribute__((ext_vector_type(8)));

#define MFMA16 __builtin_amdgcn_mfma_f32_16x16x32_bf16

// ---- ws layout (bytes) ----
#define XW_OFF  0u           // uint2[NTASK*4*64] = 41,943,040 B (bf16 D-frags)
#define EMB_OFF 41943040u    // ushort[10000*128] = 2,560,000 B
#define W1T_OFF 44503040u    // ushort[64*128]
#define U1T_OFF 44519424u    // ushort[64*64]
#define W2T_OFF 44527616u
#define U2T_OFF 44535808u    // end = 44,544,000 B

__device__ __forceinline__ unsigned f2bfu(float f) {
    union { float f; unsigned u; } x; x.f = f;
    return (x.u + 0x7fffu + ((x.u >> 16) & 1u)) >> 16;   // RNE (prep only)
}
__device__ __forceinline__ unsigned cvtpk(float lo, float hi) {
    unsigned r;
    asm("v_cvt_pk_bf16_f32 %0, %1, %2" : "=v"(r) : "v"(lo), "v"(hi));
    return r;
}
__device__ __forceinline__ float bflo(unsigned u) {
    union { unsigned u; float f; } x; x.u = u << 16; return x.f;
}
__device__ __forceinline__ float bfhi(unsigned u) {
    union { unsigned u; float f; } x; x.u = u & 0xffff0000u; return x.f;
}
// branch-free exact-tails tanh: 1 - 2/(e^{2x}+1)
__device__ __forceinline__ float fast_tanh(float x) {
    float e = __builtin_amdgcn_exp2f(x * 2.8853900817779268f);   // e^{2x}
    float r = __builtin_amdgcn_rcpf(e + 1.0f);
    return __builtin_fmaf(-2.0f, r, 1.0f);
}

// ---------------------------------------------------------------------------
// prep: bf16 tables — emb padded to K=128, transposed W1/U1/W2/U2.
// ---------------------------------------------------------------------------
__global__ __launch_bounds__(256) void prep_kernel(
    const float* __restrict__ emb, const float* __restrict__ W1,
    const float* __restrict__ U1,  const float* __restrict__ W2,
    const float* __restrict__ U2,  char* __restrict__ ws)
{
    ushort* emb_bf = (ushort*)(ws + EMB_OFF);
    ushort* w1t    = (ushort*)(ws + W1T_OFF);
    ushort* u1t    = (ushort*)(ws + U1T_OFF);
    ushort* w2t    = (ushort*)(ws + W2T_OFF);
    ushort* u2t    = (ushort*)(ws + U2T_OFF);
    const int tid    = blockIdx.x * 256 + threadIdx.x;
    const int stride = gridDim.x * 256;

    for (int i = tid; i < 10000 * 16; i += stride) {
        const int r = i >> 4, kc = (i & 15) * 8;
        unsigned w[4];
        #pragma unroll
        for (int p = 0; p < 4; ++p) {
            const int k0 = kc + 2 * p;
            unsigned lo = (k0     < EMBED) ? f2bfu(emb[r * EMBED + k0])     : 0u;
            unsigned hi = (k0 + 1 < EMBED) ? f2bfu(emb[r * EMBED + k0 + 1]) : 0u;
            w[p] = lo | (hi << 16);
        }
        uint4 v; v.x = w[0]; v.y = w[1]; v.z = w[2]; v.w = w[3];
        *(uint4*)(emb_bf + (size_t)r * 128 + kc) = v;
    }
    for (int i = tid; i < UNITS * 128; i += stride) {
        const int u = i >> 7, k = i & 127;
        w1t[i] = (k < EMBED) ? (ushort)f2bfu(W1[k * UNITS + u]) : (ushort)0;
    }
    for (int i = tid; i < UNITS * UNITS; i += stride) {
        const int u = i >> 6, k = i & 63;
        u1t[i] = (ushort)f2bfu(U1[k * UNITS + u]);
        w2t[i] = (ushort)f2bfu(W2[k * UNITS + u]);
        u2t[i] = (ushort)f2bfu(U2[k * UNITS + u]);
    }
}

// ---------------------------------------------------------------------------
// proj: xw[task][mt] = b1 + emb[tokens] @ W1 as bf16 uint2 D-fragments.
// One wave per (t, tile) task; grid exactly NTASK/4 blocks of 4 waves.
// Scan wave w reads slice mt=w: same lane, zero rearrangement.
// ---------------------------------------------------------------------------
__global__ __launch_bounds__(256) void proj_kernel(
    const int*    __restrict__ tokens,
    const float*  __restrict__ b1,
    const ushort* __restrict__ emb_bf,
    const ushort* __restrict__ w1t,
    uint2*        __restrict__ xw)
{
    const int lane = threadIdx.x & 63;
    const int wid  = threadIdx.x >> 6;
    const int m15  = lane & 15;
    const int kgrp = lane >> 4;
    const int task = blockIdx.x * 4 + wid;      // == t*NTILE + tile
    const int t    = task >> 8;                 // NTILE == 256
    const int tile = task & 255;

    // A-frags of W1^T: aW1[mt][ks] rows = unit 16mt + m15
    bf16x8 aW1[4][4];
    #pragma unroll
    for (int mt = 0; mt < 4; ++mt)
        #pragma unroll
        for (int ks = 0; ks < 4; ++ks)
            aW1[mt][ks] = *(const bf16x8*)(w1t + (16 * mt + m15) * 128 + kgrp * 8 + 32 * ks);

    const int b   = tile * 16 + m15;
    const int tok = tokens[b * SEQ + t];

    bf16x8 bf[4];
    #pragma unroll
    for (int ks = 0; ks < 4; ++ks)
        bf[ks] = *(const bf16x8*)(emb_bf + (size_t)tok * 128 + kgrp * 8 + 32 * ks);

    f32x4 acc[4];
    #pragma unroll
    for (int mt = 0; mt < 4; ++mt)
        acc[mt] = *(const f32x4*)(b1 + 16 * mt + 4 * kgrp);
    #pragma unroll
    for (int ks = 0; ks < 4; ++ks)
        #pragma unroll
        for (int mt = 0; mt < 4; ++mt)
            acc[mt] = MFMA16(aW1[mt][ks], bf[ks], acc[mt], 0, 0, 0);

    #pragma unroll
    for (int mt = 0; mt < 4; ++mt) {
        uint2 q;
        q.x = cvtpk(acc[mt][0], acc[mt][1]);
        q.y = cvtpk(acc[mt][2], acc[mt][3]);
        xw[((size_t)task * 4 + mt) * 64 + lane] = q;
    }
}

// ---------------------------------------------------------------------------
// rnn: lean scan. 4 waves/block M-split, 256 blocks (1/CU). Per phase:
// 4 ds_read -> 6 MFMA -> 8 tanh -> 4 cvt_pk -> 2 ds_write -> 1 barrier.
// xw C-init streamed from HBM, 2-phase-deep register prefetch.
// ---------------------------------------------------------------------------
__global__ __launch_bounds__(256, 1) void rnn_kernel(
    const uint2*  __restrict__ xw,
    const ushort* __restrict__ u1t,
    const ushort* __restrict__ w2t,
    const ushort* __restrict__ u2t,
    const float*  __restrict__ b2,
    const float*  __restrict__ Wo,
    const float*  __restrict__ bo,
    float*        __restrict__ out)
{
    __shared__ __align__(16) char h1L[2][2048];   // [buf][16b x 64u bf16, swz]
    __shared__ __align__(16) char h2L[2][2048];
    __shared__ float headp[4][16];

    const int lane = threadIdx.x & 63;
    const int w    = threadIdx.x >> 6;
    const int m15  = lane & 15;
    const int kgrp = lane >> 4;
    const int swz  = (m15 & 7) << 4;
    const int wg   = blockIdx.x;

    // zero h2[-1] (buf 0)
    {
        uint4 z = {0u, 0u, 0u, 0u};
        if (threadIdx.x < 128) ((uint4*)h2L[0])[threadIdx.x] = z;
    }

    const int urow = 16 * w + m15;
    bf16x8 aU1[2], aW2[2], aU2[2];
    #pragma unroll
    for (int ks = 0; ks < 2; ++ks) {
        aU1[ks] = *(const bf16x8*)(u1t + urow * 64 + kgrp * 8 + 32 * ks);
        aW2[ks] = *(const bf16x8*)(w2t + urow * 64 + kgrp * 8 + 32 * ks);
        aU2[ks] = *(const bf16x8*)(u2t + urow * 64 + kgrp * 8 + 32 * ks);
    }
    const int ubase = 16 * w + 4 * kgrp;
    const f32x4 b2c = *(const f32x4*)(b2 + ubase);

    // xw stream: element for (t) at xwp[t * TSTRIDE]
    const size_t TSTRIDE = (size_t)NTILE * 4 * 64;      // uint2 per timestep
    const uint2* xwp = xw + ((size_t)wg * 4 + w) * 64 + lane;

    uint2 q0 = xwp[0];                 // xw[0] (prologue)
    uint2 qA = xwp[TSTRIDE];           // xw[1]
    uint2 qB = xwp[2 * TSTRIDE];       // xw[2]

    // ---- prologue: h1[0] = tanh(xw[0]) -> buf 0 ----
    {
        float t0 = fast_tanh(bflo(q0.x)), t1 = fast_tanh(bfhi(q0.x));
        float t2 = fast_tanh(bflo(q0.y)), t3 = fast_tanh(bfhi(q0.y));
        uint2 pk; pk.x = cvtpk(t0, t1); pk.y = cvtpk(t2, t3);
        *(uint2*)(h1L[0] + m15 * 128 + ((32 * w + 8 * kgrp) ^ swz)) = pk;
    }
    asm volatile("s_waitcnt lgkmcnt(0)" ::: "memory");
    __builtin_amdgcn_s_barrier();

    float d2f0 = 0.f, d2f1 = 0.f, d2f2 = 0.f, d2f3 = 0.f;

#define LBAR() do { asm volatile("s_waitcnt lgkmcnt(0)" ::: "memory"); \
                    __builtin_amdgcn_s_barrier(); } while (0)
// Phase T: reads {h1[T], h2[T-1]} from bufs P; computes
//   h2[T] = tanh(b2 + W2 h1[T] + U2 h2[T-1]);  h1[T+1] = tanh(xw[T+1] + U1 h1[T])
// writes bufs Q; one barrier. qA holds xw[T+1]; prefetch xw[T+3].
#define PHASE(T, P, Q)                                                           \
  {                                                                              \
    bf16x8 bh1a = *(const bf16x8*)(h1L[P] + m15 * 128 + ((kgrp * 16     ) ^ swz)); \
    bf16x8 bh1b = *(const bf16x8*)(h1L[P] + m15 * 128 + ((kgrp * 16 + 64) ^ swz)); \
    bf16x8 bh2a = *(const bf16x8*)(h2L[P] + m15 * 128 + ((kgrp * 16     ) ^ swz)); \
    bf16x8 bh2b = *(const bf16x8*)(h2L[P] + m15 * 128 + ((kgrp * 16 + 64) ^ swz)); \
    const int tn = ((T) + 3 < SEQ) ? (T) + 3 : SEQ - 1;                          \
    uint2 qC = xwp[(size_t)tn * TSTRIDE];                                        \
    f32x4 d1 = {bflo(qA.x), bfhi(qA.x), bflo(qA.y), bfhi(qA.y)};                 \
    d1 = MFMA16(aU1[0], bh1a, d1, 0, 0, 0);                                      \
    d1 = MFMA16(aU1[1], bh1b, d1, 0, 0, 0);                                      \
    f32x4 dC = b2c;                                                              \
    dC = MFMA16(aW2[0], bh1a, dC, 0, 0, 0);                                      \
    dC = MFMA16(aW2[1], bh1b, dC, 0, 0, 0);                                      \
    f32x4 dD = {0.f, 0.f, 0.f, 0.f};                                             \
    dD = MFMA16(aU2[0], bh2a, dD, 0, 0, 0);                                      \
    dD = MFMA16(aU2[1], bh2b, dD, 0, 0, 0);                                      \
    float n0 = fast_tanh(d1[0]);                                                 \
    float n1 = fast_tanh(d1[1]);                                                 \
    float n2 = fast_tanh(d1[2]);                                                 \
    float n3 = fast_tanh(d1[3]);                                                 \
    d2f0 = fast_tanh(dC[0] + dD[0]);                                             \
    d2f1 = fast_tanh(dC[1] + dD[1]);                                             \
    d2f2 = fast_tanh(dC[2] + dD[2]);                                             \
    d2f3 = fast_tanh(dC[3] + dD[3]);                                             \
    {                                                                            \
        uint2 pk; pk.x = cvtpk(n0, n1); pk.y = cvtpk(n2, n3);                    \
        *(uint2*)(h1L[Q] + m15 * 128 + ((32 * w + 8 * kgrp) ^ swz)) = pk;        \
    }                                                                            \
    {                                                                            \
        uint2 pk; pk.x = cvtpk(d2f0, d2f1); pk.y = cvtpk(d2f2, d2f3);            \
        *(uint2*)(h2L[Q] + m15 * 128 + ((32 * w + 8 * kgrp) ^ swz)) = pk;        \
    }                                                                            \
    LBAR();                                                                      \
    qA = qB; qB = qC;                                                            \
  }

    for (int t = 0; t < SEQ; t += 2) {
        PHASE(t,     0, 1)
        PHASE(t + 1, 1, 0)
    }
#undef PHASE
#undef LBAR

    // ---- head: out[b] = sigmoid(h2[79] @ Wo + bo) ----
    const f32x4 woc = *(const f32x4*)(Wo + ubase);
    float p = d2f0 * woc[0] + d2f1 * woc[1] + d2f2 * woc[2] + d2f3 * woc[3];
    p += __shfl_xor(p, 16, 64);
    p += __shfl_xor(p, 32, 64);
    if (lane < 16) headp[w][lane] = p;
    __syncthreads();
    if (threadIdx.x < 16) {
        const float z = headp[0][threadIdx.x] + headp[1][threadIdx.x]
                      + headp[2][threadIdx.x] + headp[3][threadIdx.x] + bo[0];
        const float e = __builtin_amdgcn_exp2f(-z * 1.4426950408889634f);
        out[wg * 16 + threadIdx.x] = __builtin_amdgcn_rcpf(1.0f + e);
    }
}

extern "C" void kernel_launch(void* const* d_in, const int* in_sizes, int n_in,
                              void* d_out, int out_size, void* d_ws, size_t ws_size,
                              hipStream_t stream) {
    const int*   tokens = (const int*)  d_in[0];
    const float* emb    = (const float*)d_in[1];
    const float* W1     = (const float*)d_in[2];
    const float* U1     = (const float*)d_in[3];
    const float* b1     = (const float*)d_in[4];
    const float* W2     = (const float*)d_in[5];
    const float* U2     = (const float*)d_in[6];
    const float* b2     = (const float*)d_in[7];
    const float* Wo     = (const float*)d_in[8];
    const float* bo     = (const float*)d_in[9];
    float* out = (float*)d_out;
    char*  ws  = (char*)d_ws;

    prep_kernel<<<640, 256, 0, stream>>>(emb, W1, U1, W2, U2, ws);
    proj_kernel<<<NTASK / 4, 256, 0, stream>>>(
        tokens, b1,
        (const ushort*)(ws + EMB_OFF), (const ushort*)(ws + W1T_OFF),
        (uint2*)(ws + XW_OFF));
    rnn_kernel<<<NTILE, 256, 0, stream>>>(
        (const uint2*)(ws + XW_OFF),
        (const ushort*)(ws + U1T_OFF), (const ushort*)(ws + W2T_OFF),
        (const ushort*)(ws + U2T_OFF),
        b2, Wo, bo, out);
}

// Round 9
// 57.151 us; speedup vs baseline: 1.8393x; 1.5683x over previous
//
#include <hip/hip_runtime.h>

#define BATCH 4096
#define SEQ   80
#define EMBED 100
#define UNITS 64
#define NTILE (BATCH / 16)      // 256 batch tiles of 16 rows
#define NTASK (SEQ * NTILE)     // 20480 (t, tile) proj tasks
#define PTASK 10                // tasks per proj wave (SEQ / 8 segments)

typedef float f32x4  __attribute__((ext_vector_type(4)));
typedef short bf16x8 __attribute__((ext_vector_type(8)));

#define MFMA16 __builtin_amdgcn_mfma_f32_16x16x32_bf16

// ---- ws layout (bytes) ----
#define XW_OFF  0u           // uint2[NTASK*4*64] = 41,943,040 B (bf16 D-frags)
#define EMB_OFF 41943040u    // ushort[10000*128] = 2,560,000 B
#define W1T_OFF 44503040u    // ushort[64*128]
#define U1T_OFF 44519424u    // ushort[64*64]
#define W2T_OFF 44527616u
#define U2T_OFF 44535808u    // end = 44,544,000 B

__device__ __forceinline__ unsigned f2bfu(float f) {
    union { float f; unsigned u; } x; x.f = f;
    return (x.u + 0x7fffu + ((x.u >> 16) & 1u)) >> 16;   // RNE (prep only)
}
__device__ __forceinline__ unsigned cvtpk(float lo, float hi) {
    unsigned r;
    asm("v_cvt_pk_bf16_f32 %0, %1, %2" : "=v"(r) : "v"(lo), "v"(hi));
    return r;
}
__device__ __forceinline__ float bflo(unsigned u) {
    union { unsigned u; float f; } x; x.u = u << 16; return x.f;
}
__device__ __forceinline__ float bfhi(unsigned u) {
    union { unsigned u; float f; } x; x.u = u & 0xffff0000u; return x.f;
}
// branch-free exact-tails tanh: 1 - 2/(e^{2x}+1)
__device__ __forceinline__ float fast_tanh(float x) {
    float e = __builtin_amdgcn_exp2f(x * 2.8853900817779268f);   // e^{2x}
    float r = __builtin_amdgcn_rcpf(e + 1.0f);
    return __builtin_fmaf(-2.0f, r, 1.0f);
}

// ---------------------------------------------------------------------------
// prep: bf16 tables — emb padded to K=128, transposed W1/U1/W2/U2. (unchanged)
// ---------------------------------------------------------------------------
__global__ __launch_bounds__(256) void prep_kernel(
    const float* __restrict__ emb, const float* __restrict__ W1,
    const float* __restrict__ U1,  const float* __restrict__ W2,
    const float* __restrict__ U2,  char* __restrict__ ws)
{
    ushort* emb_bf = (ushort*)(ws + EMB_OFF);
    ushort* w1t    = (ushort*)(ws + W1T_OFF);
    ushort* u1t    = (ushort*)(ws + U1T_OFF);
    ushort* w2t    = (ushort*)(ws + W2T_OFF);
    ushort* u2t    = (ushort*)(ws + U2T_OFF);
    const int tid    = blockIdx.x * 256 + threadIdx.x;
    const int stride = gridDim.x * 256;

    for (int i = tid; i < 10000 * 16; i += stride) {
        const int r = i >> 4, kc = (i & 15) * 8;
        unsigned w[4];
        #pragma unroll
        for (int p = 0; p < 4; ++p) {
            const int k0 = kc + 2 * p;
            unsigned lo = (k0     < EMBED) ? f2bfu(emb[r * EMBED + k0])     : 0u;
            unsigned hi = (k0 + 1 < EMBED) ? f2bfu(emb[r * EMBED + k0 + 1]) : 0u;
            w[p] = lo | (hi << 16);
        }
        uint4 v; v.x = w[0]; v.y = w[1]; v.z = w[2]; v.w = w[3];
        *(uint4*)(emb_bf + (size_t)r * 128 + kc) = v;
    }
    for (int i = tid; i < UNITS * 128; i += stride) {
        const int u = i >> 7, k = i & 127;
        w1t[i] = (k < EMBED) ? (ushort)f2bfu(W1[k * UNITS + u]) : (ushort)0;
    }
    for (int i = tid; i < UNITS * UNITS; i += stride) {
        const int u = i >> 6, k = i & 63;
        u1t[i] = (ushort)f2bfu(U1[k * UNITS + u]);
        w2t[i] = (ushort)f2bfu(W2[k * UNITS + u]);
        u2t[i] = (ushort)f2bfu(U2[k * UNITS + u]);
    }
}

// ---------------------------------------------------------------------------
// proj v2: persistent waves. 2048 waves; wave (tile, tseg) computes tasks
// t = tseg*PTASK .. +PTASK-1 for its tile. A-frags/b1 loaded once; emb
// gathers for task i+1 issued before the MFMA block of task i (1-deep
// pipeline, 2-deep token prefetch). Same xw layout/rounding as R8.
// ---------------------------------------------------------------------------
__global__ __launch_bounds__(256) void proj_kernel(
    const int*    __restrict__ tokens,
    const float*  __restrict__ b1,
    const ushort* __restrict__ emb_bf,
    const ushort* __restrict__ w1t,
    uint2*        __restrict__ xw)
{
    const int lane = threadIdx.x & 63;
    const int wid  = threadIdx.x >> 6;
    const int m15  = lane & 15;
    const int kgrp = lane >> 4;
    const int gwid = blockIdx.x * 4 + wid;      // 0..2047
    const int tile = gwid & 255;
    const int t0   = (gwid >> 8) * PTASK;       // 0,10,...,70

    // A-frags of W1^T (once per wave)
    bf16x8 aW1[4][4];
    #pragma unroll
    for (int mt = 0; mt < 4; ++mt)
        #pragma unroll
        for (int ks = 0; ks < 4; ++ks)
            aW1[mt][ks] = *(const bf16x8*)(w1t + (16 * mt + m15) * 128 + kgrp * 8 + 32 * ks);
    f32x4 b1c[4];
    #pragma unroll
    for (int mt = 0; mt < 4; ++mt)
        b1c[mt] = *(const f32x4*)(b1 + 16 * mt + 4 * kgrp);

    const int b = tile * 16 + m15;
    const int* tokp = tokens + (size_t)b * SEQ;

    // prologue: gather task t0; token for t0+1
    bf16x8 cur0, cur1, cur2, cur3;
    {
        const int tk = tokp[t0];
        const ushort* er = emb_bf + (size_t)tk * 128 + kgrp * 8;
        cur0 = *(const bf16x8*)(er);      cur1 = *(const bf16x8*)(er + 32);
        cur2 = *(const bf16x8*)(er + 64); cur3 = *(const bf16x8*)(er + 96);
    }
    int tokB = tokp[t0 + 1 < SEQ ? t0 + 1 : SEQ - 1];

    #pragma unroll
    for (int i = 0; i < PTASK; ++i) {
        const int t = t0 + i;
        // issue next task's gathers first (latency hidden by MFMA below)
        bf16x8 nxt0, nxt1, nxt2, nxt3;
        {
            const ushort* er = emb_bf + (size_t)tokB * 128 + kgrp * 8;
            nxt0 = *(const bf16x8*)(er);      nxt1 = *(const bf16x8*)(er + 32);
            nxt2 = *(const bf16x8*)(er + 64); nxt3 = *(const bf16x8*)(er + 96);
        }
        {
            const int tn = t + 2;
            tokB = tokp[tn < SEQ ? (tn < t0 + PTASK ? tn : t0 + PTASK - 1) : SEQ - 1];
        }

        f32x4 acc[4];
        #pragma unroll
        for (int mt = 0; mt < 4; ++mt) acc[mt] = b1c[mt];
        #pragma unroll
        for (int mt = 0; mt < 4; ++mt) {
            acc[mt] = MFMA16(aW1[mt][0], cur0, acc[mt], 0, 0, 0);
            acc[mt] = MFMA16(aW1[mt][1], cur1, acc[mt], 0, 0, 0);
            acc[mt] = MFMA16(aW1[mt][2], cur2, acc[mt], 0, 0, 0);
            acc[mt] = MFMA16(aW1[mt][3], cur3, acc[mt], 0, 0, 0);
        }

        const size_t task = (size_t)t * NTILE + tile;
        #pragma unroll
        for (int mt = 0; mt < 4; ++mt) {
            uint2 q;
            q.x = cvtpk(acc[mt][0], acc[mt][1]);
            q.y = cvtpk(acc[mt][2], acc[mt][3]);
            xw[(task * 4 + mt) * 64 + lane] = q;
        }
        cur0 = nxt0; cur1 = nxt1; cur2 = nxt2; cur3 = nxt3;
    }
}

// ---------------------------------------------------------------------------
// rnn: lean scan (unchanged from R8 — verified). 4 waves/block M-split,
// 256 blocks. Per phase: 4 ds_read -> 6 MFMA -> 8 tanh -> 2 ds_write -> 1 bar.
// ---------------------------------------------------------------------------
__global__ __launch_bounds__(256, 1) void rnn_kernel(
    const uint2*  __restrict__ xw,
    const ushort* __restrict__ u1t,
    const ushort* __restrict__ w2t,
    const ushort* __restrict__ u2t,
    const float*  __restrict__ b2,
    const float*  __restrict__ Wo,
    const float*  __restrict__ bo,
    float*        __restrict__ out)
{
    __shared__ __align__(16) char h1L[2][2048];   // [buf][16b x 64u bf16, swz]
    __shared__ __align__(16) char h2L[2][2048];
    __shared__ float headp[4][16];

    const int lane = threadIdx.x & 63;
    const int w    = threadIdx.x >> 6;
    const int m15  = lane & 15;
    const int kgrp = lane >> 4;
    const int swz  = (m15 & 7) << 4;
    const int wg   = blockIdx.x;

    {
        uint4 z = {0u, 0u, 0u, 0u};
        if (threadIdx.x < 128) ((uint4*)h2L[0])[threadIdx.x] = z;
    }

    const int urow = 16 * w + m15;
    bf16x8 aU1[2], aW2[2], aU2[2];
    #pragma unroll
    for (int ks = 0; ks < 2; ++ks) {
        aU1[ks] = *(const bf16x8*)(u1t + urow * 64 + kgrp * 8 + 32 * ks);
        aW2[ks] = *(const bf16x8*)(w2t + urow * 64 + kgrp * 8 + 32 * ks);
        aU2[ks] = *(const bf16x8*)(u2t + urow * 64 + kgrp * 8 + 32 * ks);
    }
    const int ubase = 16 * w + 4 * kgrp;
    const f32x4 b2c = *(const f32x4*)(b2 + ubase);

    const size_t TSTRIDE = (size_t)NTILE * 4 * 64;      // uint2 per timestep
    const uint2* xwp = xw + ((size_t)wg * 4 + w) * 64 + lane;

    uint2 q0 = xwp[0];                 // xw[0]
    uint2 qA = xwp[TSTRIDE];           // xw[1]
    uint2 qB = xwp[2 * TSTRIDE];       // xw[2]

    {
        float t0 = fast_tanh(bflo(q0.x)), t1 = fast_tanh(bfhi(q0.x));
        float t2 = fast_tanh(bflo(q0.y)), t3 = fast_tanh(bfhi(q0.y));
        uint2 pk; pk.x = cvtpk(t0, t1); pk.y = cvtpk(t2, t3);
        *(uint2*)(h1L[0] + m15 * 128 + ((32 * w + 8 * kgrp) ^ swz)) = pk;
    }
    asm volatile("s_waitcnt lgkmcnt(0)" ::: "memory");
    __builtin_amdgcn_s_barrier();

    float d2f0 = 0.f, d2f1 = 0.f, d2f2 = 0.f, d2f3 = 0.f;

#define LBAR() do { asm volatile("s_waitcnt lgkmcnt(0)" ::: "memory"); \
                    __builtin_amdgcn_s_barrier(); } while (0)
#define PHASE(T, P, Q)                                                           \
  {                                                                              \
    bf16x8 bh1a = *(const bf16x8*)(h1L[P] + m15 * 128 + ((kgrp * 16     ) ^ swz)); \
    bf16x8 bh1b = *(const bf16x8*)(h1L[P] + m15 * 128 + ((kgrp * 16 + 64) ^ swz)); \
    bf16x8 bh2a = *(const bf16x8*)(h2L[P] + m15 * 128 + ((kgrp * 16     ) ^ swz)); \
    bf16x8 bh2b = *(const bf16x8*)(h2L[P] + m15 * 128 + ((kgrp * 16 + 64) ^ swz)); \
    const int tn = ((T) + 3 < SEQ) ? (T) + 3 : SEQ - 1;                          \
    uint2 qC = xwp[(size_t)tn * TSTRIDE];                                        \
    f32x4 d1 = {bflo(qA.x), bfhi(qA.x), bflo(qA.y), bfhi(qA.y)};                 \
    d1 = MFMA16(aU1[0], bh1a, d1, 0, 0, 0);                                      \
    d1 = MFMA16(aU1[1], bh1b, d1, 0, 0, 0);                                      \
    f32x4 dC = b2c;                                                              \
    dC = MFMA16(aW2[0], bh1a, dC, 0, 0, 0);                                      \
    dC = MFMA16(aW2[1], bh1b, dC, 0, 0, 0);                                      \
    f32x4 dD = {0.f, 0.f, 0.f, 0.f};                                             \
    dD = MFMA16(aU2[0], bh2a, dD, 0, 0, 0);                                      \
    dD = MFMA16(aU2[1], bh2b, dD, 0, 0, 0);                                      \
    float n0 = fast_tanh(d1[0]);                                                 \
    float n1 = fast_tanh(d1[1]);                                                 \
    float n2 = fast_tanh(d1[2]);                                                 \
    float n3 = fast_tanh(d1[3]);                                                 \
    d2f0 = fast_tanh(dC[0] + dD[0]);                                             \
    d2f1 = fast_tanh(dC[1] + dD[1]);                                             \
    d2f2 = fast_tanh(dC[2] + dD[2]);                                             \
    d2f3 = fast_tanh(dC[3] + dD[3]);                                             \
    {                                                                            \
        uint2 pk; pk.x = cvtpk(n0, n1); pk.y = cvtpk(n2, n3);                    \
        *(uint2*)(h1L[Q] + m15 * 128 + ((32 * w + 8 * kgrp) ^ swz)) = pk;        \
    }                                                                            \
    {                                                                            \
        uint2 pk; pk.x = cvtpk(d2f0, d2f1); pk.y = cvtpk(d2f2, d2f3);            \
        *(uint2*)(h2L[Q] + m15 * 128 + ((32 * w + 8 * kgrp) ^ swz)) = pk;        \
    }                                                                            \
    LBAR();                                                                      \
    qA = qB; qB = qC;                                                            \
  }

    for (int t = 0; t < SEQ; t += 2) {
        PHASE(t,     0, 1)
        PHASE(t + 1, 1, 0)
    }
#undef PHASE
#undef LBAR

    const f32x4 woc = *(const f32x4*)(Wo + ubase);
    float p = d2f0 * woc[0] + d2f1 * woc[1] + d2f2 * woc[2] + d2f3 * woc[3];
    p += __shfl_xor(p, 16, 64);
    p += __shfl_xor(p, 32, 64);
    if (lane < 16) headp[w][lane] = p;
    __syncthreads();
    if (threadIdx.x < 16) {
        const float z = headp[0][threadIdx.x] + headp[1][threadIdx.x]
                      + headp[2][threadIdx.x] + headp[3][threadIdx.x] + bo[0];
        const float e = __builtin_amdgcn_exp2f(-z * 1.4426950408889634f);
        out[wg * 16 + threadIdx.x] = __builtin_amdgcn_rcpf(1.0f + e);
    }
}

extern "C" void kernel_launch(void* const* d_in, const int* in_sizes, int n_in,
                              void* d_out, int out_size, void* d_ws, size_t ws_size,
                              hipStream_t stream) {
    const int*   tokens = (const int*)  d_in[0];
    const float* emb    = (const float*)d_in[1];
    const float* W1     = (const float*)d_in[2];
    const float* U1     = (const float*)d_in[3];
    const float* b1     = (const float*)d_in[4];
    const float* W2     = (const float*)d_in[5];
    const float* U2     = (const float*)d_in[6];
    const float* b2     = (const float*)d_in[7];
    const float* Wo     = (const float*)d_in[8];
    const float* bo     = (const float*)d_in[9];
    float* out = (float*)d_out;
    char*  ws  = (char*)d_ws;

    prep_kernel<<<640, 256, 0, stream>>>(emb, W1, U1, W2, U2, ws);
    proj_kernel<<<512, 256, 0, stream>>>(
        tokens, b1,
        (const ushort*)(ws + EMB_OFF), (const ushort*)(ws + W1T_OFF),
        (uint2*)(ws + XW_OFF));
    rnn_kernel<<<NTILE, 256, 0, stream>>>(
        (const uint2*)(ws + XW_OFF),
        (const ushort*)(ws + U1T_OFF), (const ushort*)(ws + W2T_OFF),
        (const ushort*)(ws + U2T_OFF),
        b2, Wo, bo, out);
}